// Round 2
// baseline (45.578 us; speedup 1.0000x reference)
//
#include <hip/hip_runtime.h>

#define K_TOTAL 32768
#define R_TOTAL 128
#define A_DIM   16

#define WAVES_TOTAL 2048
#define KBATCH (K_TOTAL / WAVES_TOTAL)   // 16 k-points per wave

// Single fused kernel.
//   - lane l holds rules {l, l+64}: membership constants folded to FMA form
//     (rise = x*c0+c1, fall = x*c2+c3) in VGPRs, computed once from abcd.
//   - per k: x[16] is wave-uniform -> s_load, used as SGPR operands of v_fma.
//   - per k: 6-stage shfl_xor butterfly reduces (num, den) over the 64 lanes;
//     lane j keeps k-batch element j; one coalesced 64B store at the end.
__global__ __launch_bounds__(256, 2) void fuzzy_all(const float* __restrict__ input,
                                                    const float* __restrict__ abcd,
                                                    const float* __restrict__ rho,
                                                    float* __restrict__ out) {
    const int lane  = threadIdx.x & 63;
    // wave id made explicitly scalar so kbase (and the x addresses) are uniform
    const int wid   = __builtin_amdgcn_readfirstlane(threadIdx.x >> 6);
    const int wgid  = blockIdx.x * 4 + wid;          // 0..2047, wave-uniform
    const int kbase = wgid * KBATCH;

    // ---- one-time per wave: sort abcd + fold constants for 2 rules/lane ----
    float C0[2][A_DIM], C1[2][A_DIM], C2[2][A_DIM], C3[2][A_DIM];
    float RH[2][A_DIM], BI[2];
    #pragma unroll
    for (int q = 0; q < 2; ++q) {
        const int r = lane + q * 64;
        const float4* ab = (const float4*)abcd + r * A_DIM;
        #pragma unroll
        for (int a = 0; a < A_DIM; ++a) {
            float4 v = ab[a];
            float v0 = v.x, v1 = v.y, v2 = v.z, v3 = v.w, t;
            // 5-comparator sorting network
            t = fminf(v0, v1); v1 = fmaxf(v0, v1); v0 = t;
            t = fminf(v2, v3); v3 = fmaxf(v2, v3); v2 = t;
            t = fminf(v0, v2); v2 = fmaxf(v0, v2); v0 = t;
            t = fminf(v1, v3); v3 = fmaxf(v1, v3); v1 = t;
            t = fminf(v1, v2); v2 = fmaxf(v1, v2); v1 = t;
            // v0=a, v1=b, v2=c, v3=d
            float iba = __builtin_amdgcn_rcpf(v1 - v0);
            float idc = __builtin_amdgcn_rcpf(v3 - v2);
            C0[q][a] =  iba;
            C1[q][a] = -v0 * iba;
            C2[q][a] = -idc;
            C3[q][a] =  v3 * idc;
        }
        const float* rr = rho + r * (A_DIM + 1);
        #pragma unroll
        for (int a = 0; a < A_DIM; ++a) RH[q][a] = rr[a];
        BI[q] = rr[A_DIM];
    }

    float res = 0.0f;

    #pragma unroll 4
    for (int j = 0; j < KBATCH; ++j) {
        // wave-uniform address -> s_load_dwordx4 x4, values live in SGPRs
        const float* xp = input + (kbase + j) * A_DIM;
        float sx[A_DIM];
        #pragma unroll
        for (int a4 = 0; a4 < 4; ++a4) {
            float4 xv = ((const float4*)xp)[a4];
            sx[a4*4+0] = xv.x; sx[a4*4+1] = xv.y;
            sx[a4*4+2] = xv.z; sx[a4*4+3] = xv.w;
        }

        float w0 = 1.0f, w1 = 1.0f, z0 = BI[0], z1 = BI[1];
        #pragma unroll
        for (int a = 0; a < A_DIM; ++a) {
            float xa = sx[a];
            float r0 = fmaf(xa, C0[0][a], C1[0][a]);
            float f0 = fmaf(xa, C2[0][a], C3[0][a]);
            float m0 = fmaxf(fminf(fminf(r0, f0), 1.0f), 0.0f);   // min3 + max
            w0 *= m0;
            z0 = fmaf(xa, RH[0][a], z0);
            float r1 = fmaf(xa, C0[1][a], C1[1][a]);
            float f1 = fmaf(xa, C2[1][a], C3[1][a]);
            float m1 = fmaxf(fminf(fminf(r1, f1), 1.0f), 0.0f);
            w1 *= m1;
            z1 = fmaf(xa, RH[1][a], z1);
        }
        float num = fmaf(z1, w1, z0 * w0);
        float den = w0 + w1;

        // butterfly reduce over 64 lanes (2 values)
        #pragma unroll
        for (int s = 1; s < 64; s <<= 1) {
            num += __shfl_xor(num, s, 64);
            den += __shfl_xor(den, s, 64);
        }

        float v = num * __builtin_amdgcn_rcpf(den + 1e-13f);
        res = (lane == j) ? v : res;   // lane j keeps result for k = kbase+j
    }

    if (lane < KBATCH) out[kbase + lane] = res;
}

// ---------------------------------------------------------------------------
extern "C" void kernel_launch(void* const* d_in, const int* in_sizes, int n_in,
                              void* d_out, int out_size, void* d_ws, size_t ws_size,
                              hipStream_t stream) {
    const float* input = (const float*)d_in[0];   // (K, A)    fp32
    const float* abcd  = (const float*)d_in[1];   // (R, A, 4) fp32
    const float* rho   = (const float*)d_in[2];   // (R, A+1)  fp32
    float* out = (float*)d_out;                   // (K,)      fp32

    fuzzy_all<<<WAVES_TOTAL / 4, 256, 0, stream>>>(input, abcd, rho, out);
}

// Round 3
// 25.993 us; speedup vs baseline: 1.7535x; 1.7535x over previous
//
#include <hip/hip_runtime.h>

#define K_TOTAL 32768
#define R_TOTAL 128
#define A_DIM   16
#define KBATCH  16    // k-points per block

// Block = 128 threads = 2 waves.
//   wave h (h=0,1) owns rules [h*64, h*64+64): lane l holds rule h*64+l.
//   Membership constants folded to FMA form live in VGPRs (81 floats/lane).
//   Per k: x[16] is wave-uniform -> s_load into SGPRs; every inner op is
//   v_fma(sgpr_x, vgpr_c, vgpr_c) — exactly 6 VALU per (rule, dim).
//   Per k: 6-stage shfl_xor butterfly reduces (num, den) over the 64
//   rules in the wave; lane j keeps k-batch element j (cndmask).
//   Final: 2-wave partials combined through 256 B of LDS.
__global__ __launch_bounds__(128, 4) void fuzzy_all(const float* __restrict__ input,
                                                    const float* __restrict__ abcd,
                                                    const float* __restrict__ rho,
                                                    float* __restrict__ out) {
    const int lane  = threadIdx.x & 63;
    const int half  = threadIdx.x >> 6;         // wave id: rule half
    const int r     = half * 64 + lane;         // this lane's rule
    const int kbase = blockIdx.x * KBATCH;

    // ---- one-time: sort abcd and fold constants for this lane's rule ----
    float C0[A_DIM], C1[A_DIM], C2[A_DIM], C3[A_DIM], RH[A_DIM], BI;
    {
        const float4* ab = (const float4*)abcd + r * A_DIM;
        #pragma unroll
        for (int a = 0; a < A_DIM; ++a) {
            float4 v = ab[a];
            float v0 = v.x, v1 = v.y, v2 = v.z, v3 = v.w, t;
            t = fminf(v0, v1); v1 = fmaxf(v0, v1); v0 = t;
            t = fminf(v2, v3); v3 = fmaxf(v2, v3); v2 = t;
            t = fminf(v0, v2); v2 = fmaxf(v0, v2); v0 = t;
            t = fminf(v1, v3); v3 = fmaxf(v1, v3); v1 = t;
            t = fminf(v1, v2); v2 = fmaxf(v1, v2); v1 = t;
            // v0<=v1<=v2<=v3
            float iba = __builtin_amdgcn_rcpf(v1 - v0);
            float idc = __builtin_amdgcn_rcpf(v3 - v2);
            C0[a] =  iba;
            C1[a] = -v0 * iba;
            C2[a] = -idc;
            C3[a] =  v3 * idc;
        }
        const float* rr = rho + r * (A_DIM + 1);
        #pragma unroll
        for (int a = 0; a < A_DIM; ++a) RH[a] = rr[a];
        BI = rr[A_DIM];
    }

    float resn = 0.0f, resd = 0.0f;

    #pragma unroll 4
    for (int j = 0; j < KBATCH; ++j) {
        // wave-uniform address -> scalar loads; x lives in SGPRs
        const float* xp = input + (kbase + j) * A_DIM;
        float sx[A_DIM];
        #pragma unroll
        for (int a4 = 0; a4 < 4; ++a4) {
            float4 xv = ((const float4*)xp)[a4];
            sx[a4*4+0] = xv.x; sx[a4*4+1] = xv.y;
            sx[a4*4+2] = xv.z; sx[a4*4+3] = xv.w;
        }

        float w = 1.0f, z = BI;
        #pragma unroll
        for (int a = 0; a < A_DIM; ++a) {
            float xa   = sx[a];
            float rise = fmaf(xa, C0[a], C1[a]);
            float fall = fmaf(xa, C2[a], C3[a]);
            float m    = fmaxf(fminf(fminf(rise, fall), 1.0f), 0.0f); // min3+max
            w *= m;
            z  = fmaf(xa, RH[a], z);
        }

        float nm = z * w;
        float dn = w;
        #pragma unroll
        for (int s = 1; s < 64; s <<= 1) {
            nm += __shfl_xor(nm, s, 64);
            dn += __shfl_xor(dn, s, 64);
        }

        // lane j keeps the partial for k = kbase + j
        bool sel = (lane == j);
        resn = sel ? nm : resn;
        resd = sel ? dn : resd;
    }

    // combine the two rule-halves through LDS
    __shared__ float nsh[2][KBATCH];
    __shared__ float dsh[2][KBATCH];
    if (lane < KBATCH) { nsh[half][lane] = resn; dsh[half][lane] = resd; }
    __syncthreads();

    if (threadIdx.x < KBATCH) {
        float n = nsh[0][threadIdx.x] + nsh[1][threadIdx.x];
        float d = dsh[0][threadIdx.x] + dsh[1][threadIdx.x] + 1e-13f;
        out[kbase + threadIdx.x] = n * __builtin_amdgcn_rcpf(d);
    }
}

// ---------------------------------------------------------------------------
extern "C" void kernel_launch(void* const* d_in, const int* in_sizes, int n_in,
                              void* d_out, int out_size, void* d_ws, size_t ws_size,
                              hipStream_t stream) {
    const float* input = (const float*)d_in[0];   // (K, A)    fp32
    const float* abcd  = (const float*)d_in[1];   // (R, A, 4) fp32
    const float* rho   = (const float*)d_in[2];   // (R, A+1)  fp32
    float* out = (float*)d_out;                   // (K,)      fp32

    fuzzy_all<<<K_TOTAL / KBATCH, 128, 0, stream>>>(input, abcd, rho, out);
}

// Round 4
// 18.423 us; speedup vs baseline: 2.4740x; 1.4109x over previous
//
#include <hip/hip_runtime.h>

#define K_TOTAL 32768
#define R_TOTAL 128
#define A_DIM   16

#define BLOCK_THREADS   512
#define WAVES_PER_BLOCK 8
#define RULES_PER_WAVE  (R_TOTAL / WAVES_PER_BLOCK)   // 16
#define KB              64                            // k-points per block
#define RF_STRIDE       20                            // rho row padded 17 -> 20 (16B-aligned rows: 80 B)

// One fused kernel.
//   Phase 1 (fold): block cooperatively sorts abcd and folds membership
//     constants to FMA form in LDS (coalesced global reads, done once/block).
//   Phase 2 (main): lane = k-point (64 k's per block, same 64 k's for all
//     8 waves). Wave w owns rules [w*16, w*16+16). Rule constants are read
//     as wave-uniform LDS broadcasts (conflict-free) into VGPRs, so every
//     inner op is all-VGPR: 6 VALU per (rule, dim), no cross-lane traffic.
//   Phase 3 (reduce): one 8-way LDS reduction per k, then out = num/den.
__global__ __launch_bounds__(BLOCK_THREADS, 4)
void fuzzy_all(const float* __restrict__ input,
               const float* __restrict__ abcd,
               const float* __restrict__ rho,
               float* __restrict__ out) {
    __shared__ float4 ctab[R_TOTAL * A_DIM];          // 32 KB: {c0,c1,c2,c3} per (r,a)
    __shared__ float  rf[R_TOTAL * RF_STRIDE];        // 10 KB: 16 rho + bias, padded
    __shared__ float  nsh[WAVES_PER_BLOCK][KB];       // 2 KB
    __shared__ float  dsh[WAVES_PER_BLOCK][KB];       // 2 KB

    const int t     = threadIdx.x;
    const int lane  = t & 63;
    const int wv    = __builtin_amdgcn_readfirstlane(t >> 6);
    const int kbase = blockIdx.x * KB;

    // ---------------- Phase 1: fold constants into LDS (coalesced) --------
    {
        const float4* ab4 = (const float4*)abcd;      // 2048 float4 = one per (r,a)
        #pragma unroll
        for (int i = 0; i < 4; ++i) {
            int idx = t + i * BLOCK_THREADS;          // < 2048
            float4 v = ab4[idx];
            float v0 = v.x, v1 = v.y, v2 = v.z, v3 = v.w, s;
            s = fminf(v0, v1); v1 = fmaxf(v0, v1); v0 = s;
            s = fminf(v2, v3); v3 = fmaxf(v2, v3); v2 = s;
            s = fminf(v0, v2); v2 = fmaxf(v0, v2); v0 = s;
            s = fminf(v1, v3); v3 = fmaxf(v1, v3); v1 = s;
            s = fminf(v1, v2); v2 = fmaxf(v1, v2); v1 = s;
            // v0<=v1<=v2<=v3
            float iba = __builtin_amdgcn_rcpf(v1 - v0);
            float idc = __builtin_amdgcn_rcpf(v3 - v2);
            ctab[idx] = make_float4(iba, -v0 * iba, -idc, v3 * idc);
        }
        #pragma unroll
        for (int i = 0; i < 5; ++i) {
            int f = t + i * BLOCK_THREADS;
            if (f < R_TOTAL * (A_DIM + 1)) {
                int r = f / (A_DIM + 1);              // const-div -> magic mul
                int c = f - r * (A_DIM + 1);
                rf[r * RF_STRIDE + c] = rho[f];
            }
        }
    }

    // per-lane k-point coordinates (overlaps with fold latency)
    float x[A_DIM];
    {
        const float4* xp = (const float4*)(input + (size_t)(kbase + lane) * A_DIM);
        float4 a0 = xp[0], a1 = xp[1], a2 = xp[2], a3 = xp[3];
        x[0]=a0.x;  x[1]=a0.y;  x[2]=a0.z;  x[3]=a0.w;
        x[4]=a1.x;  x[5]=a1.y;  x[6]=a1.z;  x[7]=a1.w;
        x[8]=a2.x;  x[9]=a2.y;  x[10]=a2.z; x[11]=a2.w;
        x[12]=a3.x; x[13]=a3.y; x[14]=a3.z; x[15]=a3.w;
    }

    __syncthreads();

    // ---------------- Phase 2: stream this wave's 16 rules -----------------
    float num = 0.0f, den = 0.0f;
    const int rbase = wv * RULES_PER_WAVE;

    #pragma unroll 4
    for (int rr = 0; rr < RULES_PER_WAVE; ++rr) {
        const int r = rbase + rr;
        const float4* __restrict__ cr  = &ctab[r * A_DIM];
        const float*  __restrict__ rfr = &rf[r * RF_STRIDE];

        float z = rfr[A_DIM];                          // bias (broadcast b32)
        float wg[4];
        #pragma unroll
        for (int g = 0; g < 4; ++g) {
            float4 c0 = cr[g*4+0], c1 = cr[g*4+1], c2 = cr[g*4+2], c3 = cr[g*4+3];
            float4 rh = ((const float4*)rfr)[g];       // rows are 16B-aligned (stride 80 B)
            float xa0 = x[g*4+0], xa1 = x[g*4+1], xa2 = x[g*4+2], xa3 = x[g*4+3];

            float m0 = fmaxf(fminf(fminf(fmaf(xa0, c0.x, c0.y), fmaf(xa0, c0.z, c0.w)), 1.0f), 0.0f);
            float m1 = fmaxf(fminf(fminf(fmaf(xa1, c1.x, c1.y), fmaf(xa1, c1.z, c1.w)), 1.0f), 0.0f);
            float m2 = fmaxf(fminf(fminf(fmaf(xa2, c2.x, c2.y), fmaf(xa2, c2.z, c2.w)), 1.0f), 0.0f);
            float m3 = fmaxf(fminf(fminf(fmaf(xa3, c3.x, c3.y), fmaf(xa3, c3.z, c3.w)), 1.0f), 0.0f);

            z = fmaf(xa0, rh.x, z);
            z = fmaf(xa1, rh.y, z);
            z = fmaf(xa2, rh.z, z);
            z = fmaf(xa3, rh.w, z);

            wg[g] = (m0 * m1) * (m2 * m3);
        }
        float w = (wg[0] * wg[1]) * (wg[2] * wg[3]);
        num = fmaf(z, w, num);
        den += w;
    }

    // ---------------- Phase 3: 8-way reduce across waves --------------------
    nsh[wv][lane] = num;
    dsh[wv][lane] = den;
    __syncthreads();

    if (t < KB) {
        float n = 0.0f, d = 0.0f;
        #pragma unroll
        for (int c = 0; c < WAVES_PER_BLOCK; ++c) { n += nsh[c][t]; d += dsh[c][t]; }
        out[kbase + t] = n / (d + 1e-13f);
    }
}

// ---------------------------------------------------------------------------
extern "C" void kernel_launch(void* const* d_in, const int* in_sizes, int n_in,
                              void* d_out, int out_size, void* d_ws, size_t ws_size,
                              hipStream_t stream) {
    const float* input = (const float*)d_in[0];   // (K, A)    fp32
    const float* abcd  = (const float*)d_in[1];   // (R, A, 4) fp32
    const float* rho   = (const float*)d_in[2];   // (R, A+1)  fp32
    float* out = (float*)d_out;                   // (K,)      fp32

    fuzzy_all<<<K_TOTAL / KB, BLOCK_THREADS, 0, stream>>>(input, abcd, rho, out);
}